// Round 13
// baseline (961.710 us; speedup 1.0000x reference)
//
#include <hip/hip_runtime.h>
#include <hip/hip_bf16.h>

// Decomposable attention, bf16-MFMA pipeline, chunked (Bh per side per chunk).
// R15: att+concat GEMM (K=256) -> att_fullk: stage ALL of K into LDS at once
// (4x [128][64] subtiles per operand, 128 KiB, identical swizzle/issue
// geometry to gemm_nt), ONE barrier/drain total, then 8 uninterrupted MFMA
// kk-steps. The old path paid 4x (8-load + vmcnt(0) drain + 2 barriers) for
// only 4 K-iters of work -> ~235 TF. Everything else unchanged from R14
// (proven 128^2 gemm_nt for big GEMMs, e1_rowsm fused row-softmax).
// (R21 == R15 resubmit #6: rounds 7-12 all hit GPUAcquisitionTimeout.)

using f32x4 = __attribute__((ext_vector_type(4))) float;
using s16x8 = __attribute__((ext_vector_type(8))) short;

__device__ __forceinline__ void gload_lds16(const short* g, short* l) {
  __builtin_amdgcn_global_load_lds(
      (const __attribute__((address_space(1))) unsigned int*)g,
      (__attribute__((address_space(3))) unsigned int*)l, 16, 0, 0);
}

// ---------------- GEMM: C[M,N] = A[M,K] * B[N,K]^T (+bias, relu) ----------------
// grid = (N/128, M/128, batch), block = 256. K % 64 == 0. Proven R8 kernel.
template <bool RELU, bool OUT_BF16, bool HAS_BIAS, bool SUML, bool CONCAT>
__global__ __launch_bounds__(256, 4) void gemm_nt(
    const short* __restrict__ A, const short* __restrict__ B,
    const float* __restrict__ bias, void* __restrict__ Cv, int K, int lda,
    int ldb, int ldc, long sA, long sB, long sC, const float* __restrict__ cs1,
    const float* __restrict__ cs2, int cBh) {
  __shared__ __align__(16) short As[128 * 64];
  __shared__ __align__(16) short Bs[128 * 64];
  const int t = threadIdx.x;
  const int lane = t & 63;
  const int wave = t >> 6;

  unsigned flat = (blockIdx.z * gridDim.y + blockIdx.y) * gridDim.x + blockIdx.x;
  const unsigned total = gridDim.x * gridDim.y * gridDim.z;
  unsigned bx = blockIdx.x, by = blockIdx.y, bz = blockIdx.z;
  if ((total & 7u) == 0) {
    unsigned nf = (flat & 7u) * (total >> 3) + (flat >> 3);
    bx = nf % gridDim.x;
    unsigned rest = nf / gridDim.x;
    by = rest % gridDim.y;
    bz = rest / gridDim.y;
  }
  const int m0 = by * 128;
  const int n0 = bx * 128;
  const long zb = bz;

  const int srow = t >> 3;
  const int schunk = ((t & 7) ^ (srow & 7)) * 8;
  const short* ag = A + zb * sA + (long)(m0 + srow) * lda + schunk;
  const short* bg = B + zb * sB + (long)(n0 + srow) * ldb + schunk;
  const long a32 = (long)32 * lda, b32 = (long)32 * ldb;
  short* AsW = As + wave * 512;
  short* BsW = Bs + wave * 512;

  const int fr = lane & 15;
  const int kq = lane >> 4;
  int aoff[4], boff[4];
#pragma unroll
  for (int i = 0; i < 4; ++i) {
    const int ra = (wave >> 1) * 64 + i * 16 + fr;
    const int rb = (wave & 1) * 64 + i * 16 + fr;
    aoff[i] = ra * 64 + ((kq ^ (ra & 7)) * 8);
    boff[i] = rb * 64 + ((kq ^ (rb & 7)) * 8);
  }

  f32x4 acc[4][4] = {};

  for (int it = K >> 6; it > 0; --it) {
    gload_lds16(ag, AsW);
    gload_lds16(ag + a32, AsW + 2048);
    gload_lds16(ag + 2 * a32, AsW + 4096);
    gload_lds16(ag + 3 * a32, AsW + 6144);
    gload_lds16(bg, BsW);
    gload_lds16(bg + b32, BsW + 2048);
    gload_lds16(bg + 2 * b32, BsW + 4096);
    gload_lds16(bg + 3 * b32, BsW + 6144);
    ag += 64;
    bg += 64;
    __syncthreads();
#pragma unroll
    for (int kk = 0; kk < 2; ++kk) {
      const int x = kk * 32;
      s16x8 af[4], bfv[4];
#pragma unroll
      for (int i = 0; i < 4; ++i) af[i] = *(const s16x8*)(As + (aoff[i] ^ x));
#pragma unroll
      for (int j = 0; j < 4; ++j) bfv[j] = *(const s16x8*)(Bs + (boff[j] ^ x));
#pragma unroll
      for (int i = 0; i < 4; ++i)
#pragma unroll
        for (int j = 0; j < 4; ++j)
          acc[i][j] = __builtin_amdgcn_mfma_f32_16x16x32_bf16(
              af[i], bfv[j], acc[i][j], 0, 0, 0);
    }
    __syncthreads();
  }

  const int ccol = lane & 15;
  const int crow = (lane >> 4) * 4;

  if constexpr (SUML) {
    __shared__ float ssum[128];
    if (t < 128) ssum[t] = 0.f;
    __syncthreads();
#pragma unroll
    for (int j = 0; j < 4; ++j) {
      const int lcol = (wave & 1) * 64 + j * 16 + ccol;
      float bj = HAS_BIAS ? bias[n0 + lcol] : 0.f;
      float part = 0.f;
#pragma unroll
      for (int i = 0; i < 4; ++i)
#pragma unroll
        for (int r = 0; r < 4; ++r) {
          float x = acc[i][j][r] + bj;
          if (RELU) x = fmaxf(x, 0.f);
          part += x;
        }
      atomicAdd(&ssum[lcol], part);
    }
    __syncthreads();
    if (t < 128) {
      const int split = (int)sC;
      int rb2 = m0 >> 8;
      const int side = rb2 >= split;
      rb2 -= side * split;
      atomicAdd((float*)Cv + (long)rb2 * ldc + side * (ldc >> 1) + n0 + t,
                ssum[t]);
    }
  } else {
#pragma unroll
    for (int j = 0; j < 4; ++j) {
      const int col = n0 + (wave & 1) * 64 + j * 16 + ccol;
      float bj = 0.f;
      if (HAS_BIAS) bj = bias[col];
#pragma unroll
      for (int i = 0; i < 4; ++i) {
        const int row0 = m0 + (wave >> 1) * 64 + i * 16 + crow;
#pragma unroll
        for (int r = 0; r < 4; ++r) {
          float x = acc[i][j][r] + bj;
          if (RELU) x = fmaxf(x, 0.f);
          const long idx = (long)(row0 + r) * ldc + col + zb * sC;
          if (OUT_BF16)
            ((__hip_bfloat16*)Cv)[idx] = __float2bfloat16(x);
          else
            ((float*)Cv)[idx] = x;
        }
      }
    }
    if constexpr (CONCAT) {
      const int side = (int)(zb >= (long)cBh);
      const int bb = (int)zb - side * cBh;
      const float* csrc = side ? cs2 : cs1;
      const long crowbase = (long)bb * 256;
      __hip_bfloat16* Cb = (__hip_bfloat16*)Cv + zb * sC + 512 + n0;
#pragma unroll
      for (int k = 0; k < 16; ++k) {
        const int idx = k * 256 + t;
        const int r = idx >> 5;
        const int q = idx & 31;
        const float4 v =
            *(const float4*)(csrc + (crowbase + m0 + r) * 512 + n0 + q * 4);
        union {
          ushort4 u;
          __hip_bfloat16 h[4];
        } pk;
        pk.h[0] = __float2bfloat16(v.x);
        pk.h[1] = __float2bfloat16(v.y);
        pk.h[2] = __float2bfloat16(v.z);
        pk.h[3] = __float2bfloat16(v.w);
        *(ushort4*)(Cb + (long)(m0 + r) * ldc + q * 4) = pk.u;
      }
    }
  }
}

// -------- att+concat, full-K staging (K=256): C = A[M,256] * B[N,256]^T ------
// grid = (4, 2, 2*Bh), block = 256 (4 waves). LDS = 4 x [128][64] subtiles per
// operand (128 KiB total, 1 block/CU). ONE __syncthreads (vmcnt(0) drain),
// then 8 uninterrupted kk-steps of MFMA. Epilogue: bf16 store + concat fill
// (identical to gemm_nt<false,true,false,false,true>).
__global__ __launch_bounds__(256) void att_fullk(
    const short* __restrict__ A, const short* __restrict__ B,
    void* __restrict__ Cv, int lda, int ldb, int ldc, long sA, long sB,
    long sC, const float* __restrict__ cs1, const float* __restrict__ cs2,
    int cBh) {
  __shared__ __align__(16) short As[4 * 128 * 64];
  __shared__ __align__(16) short Bs[4 * 128 * 64];
  const int t = threadIdx.x;
  const int lane = t & 63;
  const int wave = t >> 6;

  unsigned flat = (blockIdx.z * gridDim.y + blockIdx.y) * gridDim.x + blockIdx.x;
  const unsigned total = gridDim.x * gridDim.y * gridDim.z;
  unsigned bx = blockIdx.x, by = blockIdx.y, bz = blockIdx.z;
  if ((total & 7u) == 0) {
    unsigned nf = (flat & 7u) * (total >> 3) + (flat >> 3);
    bx = nf % gridDim.x;
    unsigned rest = nf / gridDim.x;
    by = rest % gridDim.y;
    bz = rest / gridDim.y;
  }
  const int m0 = by * 128;
  const int n0 = bx * 128;
  const long zb = bz;

  const int srow = t >> 3;
  const int schunk = ((t & 7) ^ (srow & 7)) * 8;
  const short* ag = A + zb * sA + (long)(m0 + srow) * lda + schunk;
  const short* bg = B + zb * sB + (long)(n0 + srow) * ldb + schunk;
  const long a32 = (long)32 * lda, b32 = (long)32 * ldb;

  // stage all 4 K-subtiles of both operands (32 issues), then one drain
#pragma unroll
  for (int kt = 0; kt < 4; ++kt) {
    short* AsW = As + kt * 8192 + wave * 512;
    short* BsW = Bs + kt * 8192 + wave * 512;
    const short* a = ag + kt * 64;
    const short* b = bg + kt * 64;
    gload_lds16(a, AsW);
    gload_lds16(a + a32, AsW + 2048);
    gload_lds16(a + 2 * a32, AsW + 4096);
    gload_lds16(a + 3 * a32, AsW + 6144);
    gload_lds16(b, BsW);
    gload_lds16(b + b32, BsW + 2048);
    gload_lds16(b + 2 * b32, BsW + 4096);
    gload_lds16(b + 3 * b32, BsW + 6144);
  }
  __syncthreads();  // single vmcnt(0)+barrier of the kernel

  const int fr = lane & 15;
  const int kq = lane >> 4;
  int aoff[4], boff[4];
#pragma unroll
  for (int i = 0; i < 4; ++i) {
    const int ra = (wave >> 1) * 64 + i * 16 + fr;
    const int rb = (wave & 1) * 64 + i * 16 + fr;
    aoff[i] = ra * 64 + ((kq ^ (ra & 7)) * 8);
    boff[i] = rb * 64 + ((kq ^ (rb & 7)) * 8);
  }

  f32x4 acc[4][4] = {};
#pragma unroll
  for (int kt = 0; kt < 4; ++kt) {
    const int base = kt * 8192;
#pragma unroll
    for (int kk = 0; kk < 2; ++kk) {
      const int x = kk * 32;
      s16x8 af[4], bfv[4];
#pragma unroll
      for (int i = 0; i < 4; ++i)
        af[i] = *(const s16x8*)(As + base + (aoff[i] ^ x));
#pragma unroll
      for (int j = 0; j < 4; ++j)
        bfv[j] = *(const s16x8*)(Bs + base + (boff[j] ^ x));
#pragma unroll
      for (int i = 0; i < 4; ++i)
#pragma unroll
        for (int j = 0; j < 4; ++j)
          acc[i][j] = __builtin_amdgcn_mfma_f32_16x16x32_bf16(
              af[i], bfv[j], acc[i][j], 0, 0, 0);
    }
  }

  // epilogue: C/D layout col=lane&15, row=(lane>>4)*4+reg; bf16, no bias/relu
  const int ccol = lane & 15;
  const int crow = (lane >> 4) * 4;
#pragma unroll
  for (int j = 0; j < 4; ++j) {
    const int col = n0 + (wave & 1) * 64 + j * 16 + ccol;
#pragma unroll
    for (int i = 0; i < 4; ++i) {
      const int row0 = m0 + (wave >> 1) * 64 + i * 16 + crow;
#pragma unroll
      for (int r = 0; r < 4; ++r) {
        const long idx = (long)(row0 + r) * ldc + col + zb * sC;
        ((__hip_bfloat16*)Cv)[idx] = __float2bfloat16(acc[i][j][r]);
      }
    }
  }
  // concat right-half fill (coalesced), identical to gemm_nt CONCAT path
  {
    const int side = (int)(zb >= (long)cBh);
    const int bb = (int)zb - side * cBh;
    const float* csrc = side ? cs2 : cs1;
    const long crowbase = (long)bb * 256;
    __hip_bfloat16* Cb = (__hip_bfloat16*)Cv + zb * sC + 512 + n0;
#pragma unroll
    for (int k = 0; k < 16; ++k) {
      const int idx = k * 256 + t;
      const int r = idx >> 5;
      const int q = idx & 31;
      const float4 v =
          *(const float4*)(csrc + (crowbase + m0 + r) * 512 + n0 + q * 4);
      union {
        ushort4 u;
        __hip_bfloat16 h[4];
      } pk;
      pk.h[0] = __float2bfloat16(v.x);
      pk.h[1] = __float2bfloat16(v.y);
      pk.h[2] = __float2bfloat16(v.z);
      pk.h[3] = __float2bfloat16(v.w);
      *(ushort4*)(Cb + (long)(m0 + r) * ldc + q * 4) = pk.u;
    }
  }
}

// -------- e1 + fused row softmax: E[i,j] = F1[i,:]*F2[j,:]; W = softmax_j(E)
__global__ __launch_bounds__(256, 4) void e1_rowsm(
    const short* __restrict__ A, const short* __restrict__ B,
    float* __restrict__ E, __hip_bfloat16* __restrict__ W) {
  __shared__ __align__(16) short As[64 * 64];
  __shared__ __align__(16) short Bs[256 * 64];
  const int t = threadIdx.x;
  const int lane = t & 63;
  const int w = t >> 6;
  const int m0 = blockIdx.x * 64;
  const long z = blockIdx.y;

  const int srow = t >> 3;
  const int schunk = ((t & 7) ^ (srow & 7)) * 8;
  const short* ag = A + z * 262144 + (long)(m0 + srow) * 1024 + schunk;
  const short* bg = B + z * 262144 + (long)srow * 1024 + schunk;
  short* AsW = As + w * 512;
  short* BsW = Bs + w * 512;

  const int fr = lane & 15;
  const int kq = lane >> 4;
  const int ra = w * 16 + fr;
  const int aoff = ra * 64 + ((kq ^ (ra & 7)) * 8);
  int boff[16];
#pragma unroll
  for (int j = 0; j < 16; ++j) {
    const int rb = j * 16 + fr;
    boff[j] = rb * 64 + ((kq ^ (rb & 7)) * 8);
  }

  f32x4 acc[16] = {};

  for (int it = 0; it < 16; ++it) {
    gload_lds16(ag, AsW);
    gload_lds16(ag + 32768, AsW + 2048);
#pragma unroll
    for (int q = 0; q < 8; ++q)
      gload_lds16(bg + (long)q * 32768, BsW + q * 2048);
    ag += 64;
    bg += 64;
    __syncthreads();
#pragma unroll
    for (int kk = 0; kk < 2; ++kk) {
      const int x = kk * 32;
      const s16x8 af = *(const s16x8*)(As + (aoff ^ x));
#pragma unroll
      for (int j = 0; j < 16; ++j) {
        const s16x8 bf = *(const s16x8*)(Bs + (boff[j] ^ x));
        acc[j] = __builtin_amdgcn_mfma_f32_16x16x32_bf16(af, bf, acc[j], 0, 0, 0);
      }
    }
    __syncthreads();
  }

  const int crow = kq * 4;
  float mx[4] = {-3.4e38f, -3.4e38f, -3.4e38f, -3.4e38f};
#pragma unroll
  for (int j = 0; j < 16; ++j)
#pragma unroll
    for (int r = 0; r < 4; ++r) mx[r] = fmaxf(mx[r], acc[j][r]);
#pragma unroll
  for (int o = 1; o < 16; o <<= 1)
#pragma unroll
    for (int r = 0; r < 4; ++r) mx[r] = fmaxf(mx[r], __shfl_xor(mx[r], o));
  float sm[4] = {0.f, 0.f, 0.f, 0.f};
#pragma unroll
  for (int j = 0; j < 16; ++j)
#pragma unroll
    for (int r = 0; r < 4; ++r) sm[r] += __expf(acc[j][r] - mx[r]);
#pragma unroll
  for (int o = 1; o < 16; o <<= 1)
#pragma unroll
    for (int r = 0; r < 4; ++r) sm[r] += __shfl_xor(sm[r], o);
  float is[4];
#pragma unroll
  for (int r = 0; r < 4; ++r) is[r] = 1.0f / sm[r];

  float* Eb = E + z * 65536;
  __hip_bfloat16* Wb = W + z * 65536;
#pragma unroll
  for (int j = 0; j < 16; ++j) {
    const int col = j * 16 + fr;
#pragma unroll
    for (int r = 0; r < 4; ++r) {
      const long idx = (long)(m0 + w * 16 + crow + r) * 256 + col;
      Eb[idx] = acc[j][r];
      Wb[idx] = __float2bfloat16(__expf(acc[j][r] - mx[r]) * is[r]);
    }
  }
}

// ---------------- helpers ----------------
struct CastArgs {
  const float* src[6];
  __hip_bfloat16* dst[6];
  long n[6];
};
__global__ void cast_many(CastArgs a) {
  const int w = blockIdx.y;
  long i = ((long)blockIdx.x * blockDim.x + threadIdx.x) * 4;
  if (i >= a.n[w]) return;
  float4 v = *(const float4*)(a.src[w] + i);
  __hip_bfloat16* o = a.dst[w] + i;
  o[0] = __float2bfloat16(v.x);
  o[1] = __float2bfloat16(v.y);
  o[2] = __float2bfloat16(v.z);
  o[3] = __float2bfloat16(v.w);
}

__global__ void cast_bf16(const float* __restrict__ in,
                          __hip_bfloat16* __restrict__ out, long n) {
  long i = ((long)blockIdx.x * blockDim.x + threadIdx.x) * 4;
  if (i >= n) return;
  float4 v = *(const float4*)(in + i);
  out[i + 0] = __float2bfloat16(v.x);
  out[i + 1] = __float2bfloat16(v.y);
  out[i + 2] = __float2bfloat16(v.z);
  out[i + 3] = __float2bfloat16(v.w);
}

__global__ void prep_sent(const float* __restrict__ s1,
                          const float* __restrict__ s2,
                          __hip_bfloat16* __restrict__ S12b,
                          __hip_bfloat16* __restrict__ STbase, int Bh) {
  __shared__ float tile[32][33];
  const int z = blockIdx.z;
  const int e0 = blockIdx.x * 32;
  const int l0 = blockIdx.y * 32;
  const int side = z >= Bh;
  const int b = z - side * Bh;
  const float* ib = (side ? s2 : s1) + (long)b * 131072;
  __hip_bfloat16* on = S12b + (long)z * 131072;
  __hip_bfloat16* ot = STbase + (long)(side ? b : (Bh + b)) * 131072;
  const int tx = threadIdx.x, ty = threadIdx.y;
#pragma unroll
  for (int k = 0; k < 4; ++k) {
    const int l = l0 + ty + 8 * k;
    const float v = ib[(long)l * 512 + e0 + tx];
    on[(long)l * 512 + e0 + tx] = __float2bfloat16(v);
    tile[ty + 8 * k][tx] = v;
  }
  __syncthreads();
#pragma unroll
  for (int k = 0; k < 4; ++k)
    ot[(long)(e0 + ty + 8 * k) * 256 + l0 + tx] =
        __float2bfloat16(tile[tx][ty + 8 * k]);
}

__global__ __launch_bounds__(256) void softmax_cols_f(
    const float* __restrict__ E, __hip_bfloat16* __restrict__ W) {
  __shared__ float tile[256][65];
  __shared__ float mred[4][64], sred[4][64];
  const int b = blockIdx.y;
  const int j0 = blockIdx.x * 64;
  const int t = threadIdx.x;
  const int jl = t & 63, s = t >> 6;
  const float* Eb = E + (long)b * 65536 + j0;
#pragma unroll
  for (int k = 0; k < 64; ++k) {
    const int i = k * 4 + s;
    tile[i][jl] = Eb[(long)i * 256 + jl];
  }
  __syncthreads();
  float m = -3.4e38f;
#pragma unroll 8
  for (int r = 0; r < 64; ++r) m = fmaxf(m, tile[s * 64 + r][jl]);
  mred[s][jl] = m;
  __syncthreads();
  m = fmaxf(fmaxf(mred[0][jl], mred[1][jl]), fmaxf(mred[2][jl], mred[3][jl]));
  float sum = 0.f;
#pragma unroll 8
  for (int r = 0; r < 64; ++r) sum += __expf(tile[s * 64 + r][jl] - m);
  sred[s][jl] = sum;
  __syncthreads();
  const int jw = t >> 2;
  const int ib = t & 3;
  const float mj = fmaxf(fmaxf(mred[0][jw], mred[1][jw]),
                         fmaxf(mred[2][jw], mred[3][jw]));
  const float isj =
      1.0f / (sred[0][jw] + sred[1][jw] + sred[2][jw] + sred[3][jw]);
  __hip_bfloat16* Wb = W + (long)b * 65536 + (long)(j0 + jw) * 256 + ib * 64;
#pragma unroll 8
  for (int r = 0; r < 64; ++r)
    Wb[r] = __float2bfloat16(__expf(tile[ib * 64 + r][jw] - mj) * isj);
}

__global__ void final_lin(const __hip_bfloat16* __restrict__ h2,
                          const float* __restrict__ w,
                          const float* __restrict__ bs,
                          float* __restrict__ out) {
  const int b = blockIdx.x;
  const int t = threadIdx.x;
  float p0 = 0.f, p1 = 0.f, p2 = 0.f;
  for (int k = t; k < 1024; k += 256) {
    const float x = __bfloat162float(h2[(long)b * 1024 + k]);
    p0 += x * w[k];
    p1 += x * w[1024 + k];
    p2 += x * w[2048 + k];
  }
  for (int o = 32; o > 0; o >>= 1) {
    p0 += __shfl_xor(p0, o);
    p1 += __shfl_xor(p1, o);
    p2 += __shfl_xor(p2, o);
  }
  __shared__ float r[4][3];
  if ((t & 63) == 0) {
    r[t >> 6][0] = p0;
    r[t >> 6][1] = p1;
    r[t >> 6][2] = p2;
  }
  __syncthreads();
  if (t < 3)
    out[b * 3 + t] = r[0][t] + r[1][t] + r[2][t] + r[3][t] + bs[t];
}

extern "C" void kernel_launch(void* const* d_in, const int* in_sizes, int n_in,
                              void* d_out, int out_size, void* d_ws,
                              size_t ws_size, hipStream_t stream) {
  const float* sent1 = (const float*)d_in[0];
  const float* sent2 = (const float*)d_in[1];
  const float* f_w1 = (const float*)d_in[2];
  const float* f_b1 = (const float*)d_in[3];
  const float* f_w2 = (const float*)d_in[4];
  const float* f_b2 = (const float*)d_in[5];
  const float* g_w1 = (const float*)d_in[6];
  const float* g_b1 = (const float*)d_in[7];
  const float* g_w2 = (const float*)d_in[8];
  const float* g_b2 = (const float*)d_in[9];
  const float* h_w1 = (const float*)d_in[10];
  const float* h_b1 = (const float*)d_in[11];
  const float* h_w2 = (const float*)d_in[12];
  const float* h_b2 = (const float*)d_in[13];
  const float* fin_w = (const float*)d_in[14];
  const float* fin_b = (const float*)d_in[15];

  char* p = (char*)d_ws;
  auto take = [&](size_t n) {
    char* r = p;
    p += (n + 255) & ~(size_t)255;
    return r;
  };
  const int Bh = (ws_size >= (size_t)220 * 1024 * 1024) ? 64 : 32;
  const int chunks = 128 / Bh;
  const long R = (long)Bh * 256;

  short* Wf1 = (short*)take(1024L * 512 * 2);
  short* Wf2 = (short*)take(1024L * 1024 * 2);
  short* Wg1 = (short*)take(1024L * 1024 * 2);
  short* Wg2 = (short*)take(1024L * 1024 * 2);
  short* Wh1 = (short*)take(1024L * 2048 * 2);
  short* Wh2 = (short*)take(1024L * 1024 * 2);
  float* SUMF = (float*)take(128L * 2048 * 4);
  short* scat = (short*)take(128L * 2048 * 2);
  short* hh = (short*)take(128L * 1024 * 2);
  short* hf = (short*)take(128L * 1024 * 2);
  char* Areg = take(2 * R * 1024 * 2);  // FHID -> GHID
  char* Breg = take(2 * R * 1024 * 2);  // F12 -> CC12
  char* Creg = take(2 * R * 512 * 2);   // S12b -> E1|W1A|W2A
  char* Dreg = take(2 * R * 512 * 2);   // [S2T | S1T]
  (void)in_sizes; (void)n_in; (void)out_size;

  short* FHID = (short*)Areg;
  short* GHID = (short*)Areg;
  short* F12 = (short*)Breg;
  short* CC12 = (short*)Breg;
  short* S12b = (short*)Creg;
  float* E1 = (float*)Creg;
  short* W1A = (short*)(Creg + (long)Bh * 262144);
  short* W2A = W1A + (long)Bh * 65536;
  short* ST = (short*)Dreg;

  hipMemsetAsync(SUMF, 0, 128L * 2048 * 4, stream);

  CastArgs ca;
  ca.src[0] = f_w1; ca.dst[0] = (__hip_bfloat16*)Wf1; ca.n[0] = 524288;
  ca.src[1] = f_w2; ca.dst[1] = (__hip_bfloat16*)Wf2; ca.n[1] = 1048576;
  ca.src[2] = g_w1; ca.dst[2] = (__hip_bfloat16*)Wg1; ca.n[2] = 1048576;
  ca.src[3] = g_w2; ca.dst[3] = (__hip_bfloat16*)Wg2; ca.n[3] = 1048576;
  ca.src[4] = h_w1; ca.dst[4] = (__hip_bfloat16*)Wh1; ca.n[4] = 2097152;
  ca.src[5] = h_w2; ca.dst[5] = (__hip_bfloat16*)Wh2; ca.n[5] = 1048576;
  cast_many<<<dim3(2048, 6), 256, 0, stream>>>(ca);

  for (int c = 0; c < chunks; ++c) {
    const float* s1 = sent1 + (long)c * R * 512;
    const float* s2 = sent2 + (long)c * R * 512;
    float* SUMF_c = SUMF + (long)c * Bh * 2048;
    const int MT = (int)(2 * R / 128);

    prep_sent<<<dim3(16, 8, 2 * Bh), dim3(32, 8), 0, stream>>>(
        s1, s2, (__hip_bfloat16*)S12b, (__hip_bfloat16*)ST, Bh);

    // ---- attend MLP f (merged sides, M = 2R) ----
    gemm_nt<true, true, true, false, false><<<dim3(8, MT, 1), 256, 0, stream>>>(
        S12b, Wf1, f_b1, FHID, 512, 512, 512, 1024, 0, 0, 0, nullptr, nullptr, 0);
    gemm_nt<true, true, true, false, false><<<dim3(8, MT, 1), 256, 0, stream>>>(
        FHID, Wf2, f_b2, F12, 1024, 1024, 1024, 1024, 0, 0, 0, nullptr, nullptr, 0);

    // ---- e1 = F1 F2^T fused with row softmax (writes E1 fp32 + W1A bf16) ----
    e1_rowsm<<<dim3(4, Bh), 256, 0, stream>>>(
        F12, F12 + R * 1024, E1, (__hip_bfloat16*)W1A);

    // ---- column softmax (reads E1) ----
    softmax_cols_f<<<dim3(4, Bh), 256, 0, stream>>>(E1, (__hip_bfloat16*)W2A);

    // ---- att (merged, full-K staging) + fused coalesced concat fill ----
    att_fullk<<<dim3(4, 2, 2 * Bh), 256, 0, stream>>>(
        W1A, ST, CC12, 256, 256, 1024, 65536, 131072, 262144, s1, s2, Bh);

    // ---- compare MLP g (merged); layer2 accumulates sum-over-L ----
    gemm_nt<true, true, true, false, false><<<dim3(8, MT, 1), 256, 0, stream>>>(
        CC12, Wg1, g_b1, GHID, 1024, 1024, 1024, 1024, 0, 0, 0, nullptr, nullptr, 0);
    gemm_nt<true, false, true, true, false><<<dim3(8, MT, 1), 256, 0, stream>>>(
        GHID, Wg2, g_b2, SUMF_c, 1024, 1024, 1024, 2048, 0, 0, Bh, nullptr, nullptr, 0);
  }

  // ---- aggregate MLP h + final linear ----
  cast_bf16<<<256, 256, 0, stream>>>(SUMF, (__hip_bfloat16*)scat, 262144);
  gemm_nt<true, true, true, false, false><<<dim3(8, 1, 1), 256, 0, stream>>>(
      scat, Wh1, h_b1, hh, 2048, 2048, 2048, 1024, 0, 0, 0, nullptr, nullptr, 0);
  gemm_nt<true, true, true, false, false><<<dim3(8, 1, 1), 256, 0, stream>>>(
      hh, Wh2, h_b2, hf, 1024, 1024, 1024, 1024, 0, 0, 0, nullptr, nullptr, 0);
  final_lin<<<128, 256, 0, stream>>>((__hip_bfloat16*)hf, fin_w, fin_b,
                                     (float*)d_out);
}

// Round 15
// 923.131 us; speedup vs baseline: 1.0418x; 1.0418x over previous
//
#include <hip/hip_runtime.h>
#include <hip/hip_bf16.h>

// Decomposable attention, bf16-MFMA pipeline, chunked (Bh per side per chunk).
// R22: att_fullk epilogue vectorized (branch (a) of R15's pre-commit: att
// improved only marginally -> store path dominates). After MFMA, As (64 KB)
// is dead: stage the 128x128 bf16 C-tile into LDS [128][132] (write spreads
// 4 row-groups over all 32 banks; 132 keeps 8B alignment), barrier, then
// coalesced 2x ushort4 row-major global stores (lanes 0-15 = 256B contig).
// Replaces 64 scalar 2B stores/thread. Everything else identical to R15
// (proven 128^2 gemm_nt big GEMMs, e1_rowsm fused row-softmax, full-K att).
// (R23 == R22 resubmit: round 14 hit GPUAcquisitionTimeout, no data.)

using f32x4 = __attribute__((ext_vector_type(4))) float;
using s16x8 = __attribute__((ext_vector_type(8))) short;

__device__ __forceinline__ void gload_lds16(const short* g, short* l) {
  __builtin_amdgcn_global_load_lds(
      (const __attribute__((address_space(1))) unsigned int*)g,
      (__attribute__((address_space(3))) unsigned int*)l, 16, 0, 0);
}

// ---------------- GEMM: C[M,N] = A[M,K] * B[N,K]^T (+bias, relu) ----------------
// grid = (N/128, M/128, batch), block = 256. K % 64 == 0. Proven R8 kernel.
template <bool RELU, bool OUT_BF16, bool HAS_BIAS, bool SUML, bool CONCAT>
__global__ __launch_bounds__(256, 4) void gemm_nt(
    const short* __restrict__ A, const short* __restrict__ B,
    const float* __restrict__ bias, void* __restrict__ Cv, int K, int lda,
    int ldb, int ldc, long sA, long sB, long sC, const float* __restrict__ cs1,
    const float* __restrict__ cs2, int cBh) {
  __shared__ __align__(16) short As[128 * 64];
  __shared__ __align__(16) short Bs[128 * 64];
  const int t = threadIdx.x;
  const int lane = t & 63;
  const int wave = t >> 6;

  unsigned flat = (blockIdx.z * gridDim.y + blockIdx.y) * gridDim.x + blockIdx.x;
  const unsigned total = gridDim.x * gridDim.y * gridDim.z;
  unsigned bx = blockIdx.x, by = blockIdx.y, bz = blockIdx.z;
  if ((total & 7u) == 0) {
    unsigned nf = (flat & 7u) * (total >> 3) + (flat >> 3);
    bx = nf % gridDim.x;
    unsigned rest = nf / gridDim.x;
    by = rest % gridDim.y;
    bz = rest / gridDim.y;
  }
  const int m0 = by * 128;
  const int n0 = bx * 128;
  const long zb = bz;

  const int srow = t >> 3;
  const int schunk = ((t & 7) ^ (srow & 7)) * 8;
  const short* ag = A + zb * sA + (long)(m0 + srow) * lda + schunk;
  const short* bg = B + zb * sB + (long)(n0 + srow) * ldb + schunk;
  const long a32 = (long)32 * lda, b32 = (long)32 * ldb;
  short* AsW = As + wave * 512;
  short* BsW = Bs + wave * 512;

  const int fr = lane & 15;
  const int kq = lane >> 4;
  int aoff[4], boff[4];
#pragma unroll
  for (int i = 0; i < 4; ++i) {
    const int ra = (wave >> 1) * 64 + i * 16 + fr;
    const int rb = (wave & 1) * 64 + i * 16 + fr;
    aoff[i] = ra * 64 + ((kq ^ (ra & 7)) * 8);
    boff[i] = rb * 64 + ((kq ^ (rb & 7)) * 8);
  }

  f32x4 acc[4][4] = {};

  for (int it = K >> 6; it > 0; --it) {
    gload_lds16(ag, AsW);
    gload_lds16(ag + a32, AsW + 2048);
    gload_lds16(ag + 2 * a32, AsW + 4096);
    gload_lds16(ag + 3 * a32, AsW + 6144);
    gload_lds16(bg, BsW);
    gload_lds16(bg + b32, BsW + 2048);
    gload_lds16(bg + 2 * b32, BsW + 4096);
    gload_lds16(bg + 3 * b32, BsW + 6144);
    ag += 64;
    bg += 64;
    __syncthreads();
#pragma unroll
    for (int kk = 0; kk < 2; ++kk) {
      const int x = kk * 32;
      s16x8 af[4], bfv[4];
#pragma unroll
      for (int i = 0; i < 4; ++i) af[i] = *(const s16x8*)(As + (aoff[i] ^ x));
#pragma unroll
      for (int j = 0; j < 4; ++j) bfv[j] = *(const s16x8*)(Bs + (boff[j] ^ x));
#pragma unroll
      for (int i = 0; i < 4; ++i)
#pragma unroll
        for (int j = 0; j < 4; ++j)
          acc[i][j] = __builtin_amdgcn_mfma_f32_16x16x32_bf16(
              af[i], bfv[j], acc[i][j], 0, 0, 0);
    }
    __syncthreads();
  }

  const int ccol = lane & 15;
  const int crow = (lane >> 4) * 4;

  if constexpr (SUML) {
    __shared__ float ssum[128];
    if (t < 128) ssum[t] = 0.f;
    __syncthreads();
#pragma unroll
    for (int j = 0; j < 4; ++j) {
      const int lcol = (wave & 1) * 64 + j * 16 + ccol;
      float bj = HAS_BIAS ? bias[n0 + lcol] : 0.f;
      float part = 0.f;
#pragma unroll
      for (int i = 0; i < 4; ++i)
#pragma unroll
        for (int r = 0; r < 4; ++r) {
          float x = acc[i][j][r] + bj;
          if (RELU) x = fmaxf(x, 0.f);
          part += x;
        }
      atomicAdd(&ssum[lcol], part);
    }
    __syncthreads();
    if (t < 128) {
      const int split = (int)sC;
      int rb2 = m0 >> 8;
      const int side = rb2 >= split;
      rb2 -= side * split;
      atomicAdd((float*)Cv + (long)rb2 * ldc + side * (ldc >> 1) + n0 + t,
                ssum[t]);
    }
  } else {
#pragma unroll
    for (int j = 0; j < 4; ++j) {
      const int col = n0 + (wave & 1) * 64 + j * 16 + ccol;
      float bj = 0.f;
      if (HAS_BIAS) bj = bias[col];
#pragma unroll
      for (int i = 0; i < 4; ++i) {
        const int row0 = m0 + (wave >> 1) * 64 + i * 16 + crow;
#pragma unroll
        for (int r = 0; r < 4; ++r) {
          float x = acc[i][j][r] + bj;
          if (RELU) x = fmaxf(x, 0.f);
          const long idx = (long)(row0 + r) * ldc + col + zb * sC;
          if (OUT_BF16)
            ((__hip_bfloat16*)Cv)[idx] = __float2bfloat16(x);
          else
            ((float*)Cv)[idx] = x;
        }
      }
    }
    if constexpr (CONCAT) {
      const int side = (int)(zb >= (long)cBh);
      const int bb = (int)zb - side * cBh;
      const float* csrc = side ? cs2 : cs1;
      const long crowbase = (long)bb * 256;
      __hip_bfloat16* Cb = (__hip_bfloat16*)Cv + zb * sC + 512 + n0;
#pragma unroll
      for (int k = 0; k < 16; ++k) {
        const int idx = k * 256 + t;
        const int r = idx >> 5;
        const int q = idx & 31;
        const float4 v =
            *(const float4*)(csrc + (crowbase + m0 + r) * 512 + n0 + q * 4);
        union {
          ushort4 u;
          __hip_bfloat16 h[4];
        } pk;
        pk.h[0] = __float2bfloat16(v.x);
        pk.h[1] = __float2bfloat16(v.y);
        pk.h[2] = __float2bfloat16(v.z);
        pk.h[3] = __float2bfloat16(v.w);
        *(ushort4*)(Cb + (long)(m0 + r) * ldc + q * 4) = pk.u;
      }
    }
  }
}

// -------- att+concat, full-K staging (K=256): C = A[M,256] * B[N,256]^T ------
// grid = (4, 2, 2*Bh), block = 256 (4 waves). LDS = 4 x [128][64] subtiles per
// operand (128 KiB total, 1 block/CU). ONE drain for the K-loop, 8
// uninterrupted kk-steps of MFMA, then LDS-staged vectorized C-store +
// coalesced concat fill.
__global__ __launch_bounds__(256) void att_fullk(
    const short* __restrict__ A, const short* __restrict__ B,
    void* __restrict__ Cv, int lda, int ldb, int ldc, long sA, long sB,
    long sC, const float* __restrict__ cs1, const float* __restrict__ cs2,
    int cBh) {
  __shared__ __align__(16) short As[4 * 128 * 64];
  __shared__ __align__(16) short Bs[4 * 128 * 64];
  const int t = threadIdx.x;
  const int lane = t & 63;
  const int wave = t >> 6;

  unsigned flat = (blockIdx.z * gridDim.y + blockIdx.y) * gridDim.x + blockIdx.x;
  const unsigned total = gridDim.x * gridDim.y * gridDim.z;
  unsigned bx = blockIdx.x, by = blockIdx.y, bz = blockIdx.z;
  if ((total & 7u) == 0) {
    unsigned nf = (flat & 7u) * (total >> 3) + (flat >> 3);
    bx = nf % gridDim.x;
    unsigned rest = nf / gridDim.x;
    by = rest % gridDim.y;
    bz = rest / gridDim.y;
  }
  const int m0 = by * 128;
  const int n0 = bx * 128;
  const long zb = bz;

  const int srow = t >> 3;
  const int schunk = ((t & 7) ^ (srow & 7)) * 8;
  const short* ag = A + zb * sA + (long)(m0 + srow) * lda + schunk;
  const short* bg = B + zb * sB + (long)(n0 + srow) * ldb + schunk;
  const long a32 = (long)32 * lda, b32 = (long)32 * ldb;

  // stage all 4 K-subtiles of both operands (32 issues), then one drain
#pragma unroll
  for (int kt = 0; kt < 4; ++kt) {
    short* AsW = As + kt * 8192 + wave * 512;
    short* BsW = Bs + kt * 8192 + wave * 512;
    const short* a = ag + kt * 64;
    const short* b = bg + kt * 64;
    gload_lds16(a, AsW);
    gload_lds16(a + a32, AsW + 2048);
    gload_lds16(a + 2 * a32, AsW + 4096);
    gload_lds16(a + 3 * a32, AsW + 6144);
    gload_lds16(b, BsW);
    gload_lds16(b + b32, BsW + 2048);
    gload_lds16(b + 2 * b32, BsW + 4096);
    gload_lds16(b + 3 * b32, BsW + 6144);
  }
  __syncthreads();  // single vmcnt(0)+barrier of the K path

  const int fr = lane & 15;
  const int kq = lane >> 4;
  int aoff[4], boff[4];
#pragma unroll
  for (int i = 0; i < 4; ++i) {
    const int ra = (wave >> 1) * 64 + i * 16 + fr;
    const int rb = (wave & 1) * 64 + i * 16 + fr;
    aoff[i] = ra * 64 + ((kq ^ (ra & 7)) * 8);
    boff[i] = rb * 64 + ((kq ^ (rb & 7)) * 8);
  }

  f32x4 acc[4][4] = {};
#pragma unroll
  for (int kt = 0; kt < 4; ++kt) {
    const int base = kt * 8192;
#pragma unroll
    for (int kk = 0; kk < 2; ++kk) {
      const int x = kk * 32;
      s16x8 af[4], bfv[4];
#pragma unroll
      for (int i = 0; i < 4; ++i)
        af[i] = *(const s16x8*)(As + base + (aoff[i] ^ x));
#pragma unroll
      for (int j = 0; j < 4; ++j)
        bfv[j] = *(const s16x8*)(Bs + base + (boff[j] ^ x));
#pragma unroll
      for (int i = 0; i < 4; ++i)
#pragma unroll
        for (int j = 0; j < 4; ++j)
          acc[i][j] = __builtin_amdgcn_mfma_f32_16x16x32_bf16(
              af[i], bfv[j], acc[i][j], 0, 0, 0);
    }
  }

  // ---- vectorized C-store via LDS bf16 staging (As dead after MFMA) ----
  // C/D layout col=lane&15, row=(lane>>4)*4+reg [m89/m91-verified].
  const int ccol = lane & 15;
  const int crow = (lane >> 4) * 4;
  __syncthreads();  // all K-loop LDS reads complete before overwrite
  unsigned short* Ts = (unsigned short*)As;  // [128][132] bf16, 33 KB
#pragma unroll
  for (int j = 0; j < 4; ++j) {
    const int col = (wave & 1) * 64 + j * 16 + ccol;
#pragma unroll
    for (int i = 0; i < 4; ++i) {
      const int row0 = (wave >> 1) * 64 + i * 16 + crow;
#pragma unroll
      for (int r = 0; r < 4; ++r) {
        union {
          unsigned short u;
          __hip_bfloat16 h;
        } cv;
        cv.h = __float2bfloat16(acc[i][j][r]);
        Ts[(row0 + r) * 132 + col] = cv.u;
      }
    }
  }
  __syncthreads();
  {
    unsigned short* Cl = (unsigned short*)Cv + zb * sC + n0;
#pragma unroll
    for (int k = 0; k < 8; ++k) {
      const int vid = k * 256 + t;  // 0..2047 = 128 rows x 16 groups
      const int r = vid >> 4;
      const int g = vid & 15;
      const ushort4 lo = *(const ushort4*)(Ts + r * 132 + g * 8);
      const ushort4 hi = *(const ushort4*)(Ts + r * 132 + g * 8 + 4);
      unsigned short* dst = Cl + (long)(m0 + r) * ldc + g * 8;
      *(ushort4*)dst = lo;
      *(ushort4*)(dst + 4) = hi;
    }
  }
  // concat right-half fill (coalesced), identical to gemm_nt CONCAT path
  {
    const int side = (int)(zb >= (long)cBh);
    const int bb = (int)zb - side * cBh;
    const float* csrc = side ? cs2 : cs1;
    const long crowbase = (long)bb * 256;
    __hip_bfloat16* Cb = (__hip_bfloat16*)Cv + zb * sC + 512 + n0;
#pragma unroll
    for (int k = 0; k < 16; ++k) {
      const int idx = k * 256 + t;
      const int r = idx >> 5;
      const int q = idx & 31;
      const float4 v =
          *(const float4*)(csrc + (crowbase + m0 + r) * 512 + n0 + q * 4);
      union {
        ushort4 u;
        __hip_bfloat16 h[4];
      } pk;
      pk.h[0] = __float2bfloat16(v.x);
      pk.h[1] = __float2bfloat16(v.y);
      pk.h[2] = __float2bfloat16(v.z);
      pk.h[3] = __float2bfloat16(v.w);
      *(ushort4*)(Cb + (long)(m0 + r) * ldc + q * 4) = pk.u;
    }
  }
}

// -------- e1 + fused row softmax: E[i,j] = F1[i,:]*F2[j,:]; W = softmax_j(E)
__global__ __launch_bounds__(256, 4) void e1_rowsm(
    const short* __restrict__ A, const short* __restrict__ B,
    float* __restrict__ E, __hip_bfloat16* __restrict__ W) {
  __shared__ __align__(16) short As[64 * 64];
  __shared__ __align__(16) short Bs[256 * 64];
  const int t = threadIdx.x;
  const int lane = t & 63;
  const int w = t >> 6;
  const int m0 = blockIdx.x * 64;
  const long z = blockIdx.y;

  const int srow = t >> 3;
  const int schunk = ((t & 7) ^ (srow & 7)) * 8;
  const short* ag = A + z * 262144 + (long)(m0 + srow) * 1024 + schunk;
  const short* bg = B + z * 262144 + (long)srow * 1024 + schunk;
  short* AsW = As + w * 512;
  short* BsW = Bs + w * 512;

  const int fr = lane & 15;
  const int kq = lane >> 4;
  const int ra = w * 16 + fr;
  const int aoff = ra * 64 + ((kq ^ (ra & 7)) * 8);
  int boff[16];
#pragma unroll
  for (int j = 0; j < 16; ++j) {
    const int rb = j * 16 + fr;
    boff[j] = rb * 64 + ((kq ^ (rb & 7)) * 8);
  }

  f32x4 acc[16] = {};

  for (int it = 0; it < 16; ++it) {
    gload_lds16(ag, AsW);
    gload_lds16(ag + 32768, AsW + 2048);
#pragma unroll
    for (int q = 0; q < 8; ++q)
      gload_lds16(bg + (long)q * 32768, BsW + q * 2048);
    ag += 64;
    bg += 64;
    __syncthreads();
#pragma unroll
    for (int kk = 0; kk < 2; ++kk) {
      const int x = kk * 32;
      const s16x8 af = *(const s16x8*)(As + (aoff ^ x));
#pragma unroll
      for (int j = 0; j < 16; ++j) {
        const s16x8 bf = *(const s16x8*)(Bs + (boff[j] ^ x));
        acc[j] = __builtin_amdgcn_mfma_f32_16x16x32_bf16(af, bf, acc[j], 0, 0, 0);
      }
    }
    __syncthreads();
  }

  const int crow = kq * 4;
  float mx[4] = {-3.4e38f, -3.4e38f, -3.4e38f, -3.4e38f};
#pragma unroll
  for (int j = 0; j < 16; ++j)
#pragma unroll
    for (int r = 0; r < 4; ++r) mx[r] = fmaxf(mx[r], acc[j][r]);
#pragma unroll
  for (int o = 1; o < 16; o <<= 1)
#pragma unroll
    for (int r = 0; r < 4; ++r) mx[r] = fmaxf(mx[r], __shfl_xor(mx[r], o));
  float sm[4] = {0.f, 0.f, 0.f, 0.f};
#pragma unroll
  for (int j = 0; j < 16; ++j)
#pragma unroll
    for (int r = 0; r < 4; ++r) sm[r] += __expf(acc[j][r] - mx[r]);
#pragma unroll
  for (int o = 1; o < 16; o <<= 1)
#pragma unroll
    for (int r = 0; r < 4; ++r) sm[r] += __shfl_xor(sm[r], o);
  float is[4];
#pragma unroll
  for (int r = 0; r < 4; ++r) is[r] = 1.0f / sm[r];

  float* Eb = E + z * 65536;
  __hip_bfloat16* Wb = W + z * 65536;
#pragma unroll
  for (int j = 0; j < 16; ++j) {
    const int col = j * 16 + fr;
#pragma unroll
    for (int r = 0; r < 4; ++r) {
      const long idx = (long)(m0 + w * 16 + crow + r) * 256 + col;
      Eb[idx] = acc[j][r];
      Wb[idx] = __float2bfloat16(__expf(acc[j][r] - mx[r]) * is[r]);
    }
  }
}

// ---------------- helpers ----------------
struct CastArgs {
  const float* src[6];
  __hip_bfloat16* dst[6];
  long n[6];
};
__global__ void cast_many(CastArgs a) {
  const int w = blockIdx.y;
  long i = ((long)blockIdx.x * blockDim.x + threadIdx.x) * 4;
  if (i >= a.n[w]) return;
  float4 v = *(const float4*)(a.src[w] + i);
  __hip_bfloat16* o = a.dst[w] + i;
  o[0] = __float2bfloat16(v.x);
  o[1] = __float2bfloat16(v.y);
  o[2] = __float2bfloat16(v.z);
  o[3] = __float2bfloat16(v.w);
}

__global__ void cast_bf16(const float* __restrict__ in,
                          __hip_bfloat16* __restrict__ out, long n) {
  long i = ((long)blockIdx.x * blockDim.x + threadIdx.x) * 4;
  if (i >= n) return;
  float4 v = *(const float4*)(in + i);
  out[i + 0] = __float2bfloat16(v.x);
  out[i + 1] = __float2bfloat16(v.y);
  out[i + 2] = __float2bfloat16(v.z);
  out[i + 3] = __float2bfloat16(v.w);
}

__global__ void prep_sent(const float* __restrict__ s1,
                          const float* __restrict__ s2,
                          __hip_bfloat16* __restrict__ S12b,
                          __hip_bfloat16* __restrict__ STbase, int Bh) {
  __shared__ float tile[32][33];
  const int z = blockIdx.z;
  const int e0 = blockIdx.x * 32;
  const int l0 = blockIdx.y * 32;
  const int side = z >= Bh;
  const int b = z - side * Bh;
  const float* ib = (side ? s2 : s1) + (long)b * 131072;
  __hip_bfloat16* on = S12b + (long)z * 131072;
  __hip_bfloat16* ot = STbase + (long)(side ? b : (Bh + b)) * 131072;
  const int tx = threadIdx.x, ty = threadIdx.y;
#pragma unroll
  for (int k = 0; k < 4; ++k) {
    const int l = l0 + ty + 8 * k;
    const float v = ib[(long)l * 512 + e0 + tx];
    on[(long)l * 512 + e0 + tx] = __float2bfloat16(v);
    tile[ty + 8 * k][tx] = v;
  }
  __syncthreads();
#pragma unroll
  for (int k = 0; k < 4; ++k)
    ot[(long)(e0 + ty + 8 * k) * 256 + l0 + tx] =
        __float2bfloat16(tile[tx][ty + 8 * k]);
}

__global__ __launch_bounds__(256) void softmax_cols_f(
    const float* __restrict__ E, __hip_bfloat16* __restrict__ W) {
  __shared__ float tile[256][65];
  __shared__ float mred[4][64], sred[4][64];
  const int b = blockIdx.y;
  const int j0 = blockIdx.x * 64;
  const int t = threadIdx.x;
  const int jl = t & 63, s = t >> 6;
  const float* Eb = E + (long)b * 65536 + j0;
#pragma unroll
  for (int k = 0; k < 64; ++k) {
    const int i = k * 4 + s;
    tile[i][jl] = Eb[(long)i * 256 + jl];
  }
  __syncthreads();
  float m = -3.4e38f;
#pragma unroll 8
  for (int r = 0; r < 64; ++r) m = fmaxf(m, tile[s * 64 + r][jl]);
  mred[s][jl] = m;
  __syncthreads();
  m = fmaxf(fmaxf(mred[0][jl], mred[1][jl]), fmaxf(mred[2][jl], mred[3][jl]));
  float sum = 0.f;
#pragma unroll 8
  for (int r = 0; r < 64; ++r) sum += __expf(tile[s * 64 + r][jl] - m);
  sred[s][jl] = sum;
  __syncthreads();
  const int jw = t >> 2;
  const int ib = t & 3;
  const float mj = fmaxf(fmaxf(mred[0][jw], mred[1][jw]),
                         fmaxf(mred[2][jw], mred[3][jw]));
  const float isj =
      1.0f / (sred[0][jw] + sred[1][jw] + sred[2][jw] + sred[3][jw]);
  __hip_bfloat16* Wb = W + (long)b * 65536 + (long)(j0 + jw) * 256 + ib * 64;
#pragma unroll 8
  for (int r = 0; r < 64; ++r)
    Wb[r] = __float2bfloat16(__expf(tile[ib * 64 + r][jw] - mj) * isj);
}

__global__ void final_lin(const __hip_bfloat16* __restrict__ h2,
                          const float* __restrict__ w,
                          const float* __restrict__ bs,
                          float* __restrict__ out) {
  const int b = blockIdx.x;
  const int t = threadIdx.x;
  float p0 = 0.f, p1 = 0.f, p2 = 0.f;
  for (int k = t; k < 1024; k += 256) {
    const float x = __bfloat162float(h2[(long)b * 1024 + k]);
    p0 += x * w[k];
    p1 += x * w[1024 + k];
    p2 += x * w[2048 + k];
  }
  for (int o = 32; o > 0; o >>= 1) {
    p0 += __shfl_xor(p0, o);
    p1 += __shfl_xor(p1, o);
    p2 += __shfl_xor(p2, o);
  }
  __shared__ float r[4][3];
  if ((t & 63) == 0) {
    r[t >> 6][0] = p0;
    r[t >> 6][1] = p1;
    r[t >> 6][2] = p2;
  }
  __syncthreads();
  if (t < 3)
    out[b * 3 + t] = r[0][t] + r[1][t] + r[2][t] + r[3][t] + bs[t];
}

extern "C" void kernel_launch(void* const* d_in, const int* in_sizes, int n_in,
                              void* d_out, int out_size, void* d_ws,
                              size_t ws_size, hipStream_t stream) {
  const float* sent1 = (const float*)d_in[0];
  const float* sent2 = (const float*)d_in[1];
  const float* f_w1 = (const float*)d_in[2];
  const float* f_b1 = (const float*)d_in[3];
  const float* f_w2 = (const float*)d_in[4];
  const float* f_b2 = (const float*)d_in[5];
  const float* g_w1 = (const float*)d_in[6];
  const float* g_b1 = (const float*)d_in[7];
  const float* g_w2 = (const float*)d_in[8];
  const float* g_b2 = (const float*)d_in[9];
  const float* h_w1 = (const float*)d_in[10];
  const float* h_b1 = (const float*)d_in[11];
  const float* h_w2 = (const float*)d_in[12];
  const float* h_b2 = (const float*)d_in[13];
  const float* fin_w = (const float*)d_in[14];
  const float* fin_b = (const float*)d_in[15];

  char* p = (char*)d_ws;
  auto take = [&](size_t n) {
    char* r = p;
    p += (n + 255) & ~(size_t)255;
    return r;
  };
  const int Bh = (ws_size >= (size_t)220 * 1024 * 1024) ? 64 : 32;
  const int chunks = 128 / Bh;
  const long R = (long)Bh * 256;

  short* Wf1 = (short*)take(1024L * 512 * 2);
  short* Wf2 = (short*)take(1024L * 1024 * 2);
  short* Wg1 = (short*)take(1024L * 1024 * 2);
  short* Wg2 = (short*)take(1024L * 1024 * 2);
  short* Wh1 = (short*)take(1024L * 2048 * 2);
  short* Wh2 = (short*)take(1024L * 1024 * 2);
  float* SUMF = (float*)take(128L * 2048 * 4);
  short* scat = (short*)take(128L * 2048 * 2);
  short* hh = (short*)take(128L * 1024 * 2);
  short* hf = (short*)take(128L * 1024 * 2);
  char* Areg = take(2 * R * 1024 * 2);  // FHID -> GHID
  char* Breg = take(2 * R * 1024 * 2);  // F12 -> CC12
  char* Creg = take(2 * R * 512 * 2);   // S12b -> E1|W1A|W2A
  char* Dreg = take(2 * R * 512 * 2);   // [S2T | S1T]
  (void)in_sizes; (void)n_in; (void)out_size;

  short* FHID = (short*)Areg;
  short* GHID = (short*)Areg;
  short* F12 = (short*)Breg;
  short* CC12 = (short*)Breg;
  short* S12b = (short*)Creg;
  float* E1 = (float*)Creg;
  short* W1A = (short*)(Creg + (long)Bh * 262144);
  short* W2A = W1A + (long)Bh * 65536;
  short* ST = (short*)Dreg;

  hipMemsetAsync(SUMF, 0, 128L * 2048 * 4, stream);

  CastArgs ca;
  ca.src[0] = f_w1; ca.dst[0] = (__hip_bfloat16*)Wf1; ca.n[0] = 524288;
  ca.src[1] = f_w2; ca.dst[1] = (__hip_bfloat16*)Wf2; ca.n[1] = 1048576;
  ca.src[2] = g_w1; ca.dst[2] = (__hip_bfloat16*)Wg1; ca.n[2] = 1048576;
  ca.src[3] = g_w2; ca.dst[3] = (__hip_bfloat16*)Wg2; ca.n[3] = 1048576;
  ca.src[4] = h_w1; ca.dst[4] = (__hip_bfloat16*)Wh1; ca.n[4] = 2097152;
  ca.src[5] = h_w2; ca.dst[5] = (__hip_bfloat16*)Wh2; ca.n[5] = 1048576;
  cast_many<<<dim3(2048, 6), 256, 0, stream>>>(ca);

  for (int c = 0; c < chunks; ++c) {
    const float* s1 = sent1 + (long)c * R * 512;
    const float* s2 = sent2 + (long)c * R * 512;
    float* SUMF_c = SUMF + (long)c * Bh * 2048;
    const int MT = (int)(2 * R / 128);

    prep_sent<<<dim3(16, 8, 2 * Bh), dim3(32, 8), 0, stream>>>(
        s1, s2, (__hip_bfloat16*)S12b, (__hip_bfloat16*)ST, Bh);

    // ---- attend MLP f (merged sides, M = 2R) ----
    gemm_nt<true, true, true, false, false><<<dim3(8, MT, 1), 256, 0, stream>>>(
        S12b, Wf1, f_b1, FHID, 512, 512, 512, 1024, 0, 0, 0, nullptr, nullptr, 0);
    gemm_nt<true, true, true, false, false><<<dim3(8, MT, 1), 256, 0, stream>>>(
        FHID, Wf2, f_b2, F12, 1024, 1024, 1024, 1024, 0, 0, 0, nullptr, nullptr, 0);

    // ---- e1 = F1 F2^T fused with row softmax (writes E1 fp32 + W1A bf16) ----
    e1_rowsm<<<dim3(4, Bh), 256, 0, stream>>>(
        F12, F12 + R * 1024, E1, (__hip_bfloat16*)W1A);

    // ---- column softmax (reads E1) ----
    softmax_cols_f<<<dim3(4, Bh), 256, 0, stream>>>(E1, (__hip_bfloat16*)W2A);

    // ---- att (merged, full-K staging) + fused coalesced concat fill ----
    att_fullk<<<dim3(4, 2, 2 * Bh), 256, 0, stream>>>(
        W1A, ST, CC12, 256, 256, 1024, 65536, 131072, 262144, s1, s2, Bh);

    // ---- compare MLP g (merged); layer2 accumulates sum-over-L ----
    gemm_nt<true, true, true, false, false><<<dim3(8, MT, 1), 256, 0, stream>>>(
        CC12, Wg1, g_b1, GHID, 1024, 1024, 1024, 1024, 0, 0, 0, nullptr, nullptr, 0);
    gemm_nt<true, false, true, true, false><<<dim3(8, MT, 1), 256, 0, stream>>>(
        GHID, Wg2, g_b2, SUMF_c, 1024, 1024, 1024, 2048, 0, 0, Bh, nullptr, nullptr, 0);
  }

  // ---- aggregate MLP h + final linear ----
  cast_bf16<<<256, 256, 0, stream>>>(SUMF, (__hip_bfloat16*)scat, 262144);
  gemm_nt<true, true, true, false, false><<<dim3(8, 1, 1), 256, 0, stream>>>(
      scat, Wh1, h_b1, hh, 2048, 2048, 2048, 1024, 0, 0, 0, nullptr, nullptr, 0);
  gemm_nt<true, true, true, false, false><<<dim3(8, 1, 1), 256, 0, stream>>>(
      hh, Wh2, h_b2, hf, 1024, 1024, 1024, 1024, 0, 0, 0, nullptr, nullptr, 0);
  final_lin<<<128, 256, 0, stream>>>((__hip_bfloat16*)hf, fin_w, fin_b,
                                     (float*)d_out);
}